// Round 3
// baseline (7601.751 us; speedup 1.0000x reference)
//
#include <hip/hip_runtime.h>

// TGRec — DIAGNOSTIC BISECTION ROUND.
// Output 0 (merged): direct reference-faithful per-batch kernel (no d_ws).
// Output 1 (attn_sq): fast path (k_qproj -> k_qkproj -> k_attn).
// If out0 passes & out1 fails -> fast q/qk/attn path indexing bug.
// If both pass -> bug was in the old epilogue / s-accumulation.
// If out0 fails -> harness interface assumption wrong.

__device__ __forceinline__ void fma4(float4& a, float s, const float4& w) {
  a.x = fmaf(s, w.x, a.x); a.y = fmaf(s, w.y, a.y);
  a.z = fmaf(s, w.z, a.z); a.w = fmaf(s, w.w, a.w);
}
__device__ __forceinline__ float dot4(const float4& a, const float4& b) {
  return a.x * b.x + a.y * b.y + a.z * b.z + a.w * b.w;
}

// ---------------------------------------------------------------------------
// Direct per-batch kernel: computes merged (always) and att (if writeAtt).
__global__ __launch_bounds__(256) void k_direct(
    const float* __restrict__ src, const float* __restrict__ srct,
    const float* __restrict__ seq, const float* __restrict__ seqt,
    const unsigned int* __restrict__ mw, const float* __restrict__ w_qs,
    const float* __restrict__ w_ks, const float* __restrict__ w_vs,
    const float* __restrict__ fc_w, const float* __restrict__ fc_b,
    const float* __restrict__ ln_g, const float* __restrict__ ln_b,
    const float* __restrict__ fc1_w, const float* __restrict__ fc1_b,
    const float* __restrict__ fc2_w, const float* __restrict__ fc2_b,
    float* __restrict__ out, float* __restrict__ att, int writeAtt) {
  __shared__ float kin[64 * 256];   // k_in rows
  __shared__ float qin[256];        // q_in
  __shared__ float qv[256];         // q projection
  __shared__ float plog[64 * 8];    // partial logits [n][h*4+p]
  __shared__ float lbuf[2 * 64];    // softmax scratch
  __shared__ float aw[2 * 64];      // attention weights
  __shared__ float sv[2 * 256];     // attn-weighted k_in per head
  __shared__ float ov[256];         // attention output (v-projected)
  __shared__ float xx[256];         // fc + residual
  __shared__ float hcat[384];       // [ln | src]
  __shared__ float h1[128];         // relu(fc1)
  __shared__ float stats[2];
  const int tid = threadIdx.x;
  const int b = blockIdx.x;

  // load k_in = [seq | seq_t]
#pragma unroll
  for (int i = 0; i < 16; ++i) {
    const int f4 = i * 256 + tid;
    const int n = f4 >> 6;
    const int c = (f4 & 63) * 4;
    float4 v = (c < 128)
                   ? *(const float4*)&seq[(b * 64 + n) * 128 + c]
                   : *(const float4*)&seqt[(b * 64 + n) * 128 + (c - 128)];
    *(float4*)&kin[n * 256 + c] = v;
  }
  if (tid < 64) {
    const int c = tid * 4;
    float4 v = (c < 128) ? *(const float4*)&src[b * 128 + c]
                         : *(const float4*)&srct[b * 128 + (c - 128)];
    *(float4*)&qin[c] = v;
  }
  __syncthreads();

  // q[j] = sum_t q_in[t] * w_qs[t, j]
  {
    float acc = 0.f;
    for (int t = 0; t < 256; ++t) acc += qin[t] * w_qs[t * 256 + tid];
    qv[tid] = acc;
  }
  __syncthreads();

  // k-projection + partial logits: thread (n = tid>>2, p = tid&3) handles
  // d in [32p, 32p+32) for both heads.
  {
    const int n = tid >> 2, p = tid & 3;
    for (int h = 0; h < 2; ++h) {
      float pl = 0.f;
      for (int dd = 0; dd < 32; ++dd) {
        const int col = h * 128 + p * 32 + dd;
        float kacc = 0.f;
        for (int t = 0; t < 256; t += 4) {
          const float4 kv4 = *(const float4*)&kin[n * 256 + t];
          kacc += kv4.x * w_ks[(t + 0) * 256 + col] +
                  kv4.y * w_ks[(t + 1) * 256 + col] +
                  kv4.z * w_ks[(t + 2) * 256 + col] +
                  kv4.w * w_ks[(t + 3) * 256 + col];
        }
        pl += qv[col] * kacc;
      }
      plog[n * 8 + h * 4 + p] = pl;
    }
  }
  __syncthreads();

  // logits -> mask -> softmax (reference-faithful, max-subtracted)
  if (tid < 2) {
    const int h = tid;
    float m = -1e30f;
    for (int n = 0; n < 64; ++n) {
      float lg = (plog[n * 8 + h * 4 + 0] + plog[n * 8 + h * 4 + 1] +
                  plog[n * 8 + h * 4 + 2] + plog[n * 8 + h * 4 + 3]) *
                 0.08838834764831845f;
      if (mw[b * 64 + n] != 0u) lg = -1e10f;
      lbuf[h * 64 + n] = lg;
      m = fmaxf(m, lg);
    }
    float den = 0.f;
    for (int n = 0; n < 64; ++n) {
      const float e = __expf(lbuf[h * 64 + n] - m);
      lbuf[h * 64 + n] = e;
      den += e;
    }
    const float inv = 1.0f / den;
    for (int n = 0; n < 64; ++n) aw[h * 64 + n] = lbuf[h * 64 + n] * inv;
  }
  __syncthreads();
  if (writeAtt && tid < 128) {
    const int h = tid >> 6, n = tid & 63;
    att[h * (4096 * 64) + b * 64 + n] = aw[h * 64 + n];
  }

  // sv_h[t] = sum_n aw[h][n] * kin[n][t]
#pragma unroll
  for (int i = 0; i < 2; ++i) {
    const int idx = i * 256 + tid;
    const int h = idx >> 8, t = idx & 255;
    float a = 0.f;
    for (int n = 0; n < 64; ++n) a += aw[h * 64 + n] * kin[n * 256 + t];
    sv[h * 256 + t] = a;
  }
  __syncthreads();

  // ov[j] = sum_t sv_h(j)[t] * w_vs[t, j]
  {
    const int h = tid >> 7;
    float acc = 0.f;
    for (int t = 0; t < 256; ++t) acc += sv[h * 256 + t] * w_vs[t * 256 + tid];
    ov[tid] = acc;
  }
  __syncthreads();

  // x[j] = ov @ fc_w + fc_b + q_in
  {
    float acc = 0.f;
    for (int d = 0; d < 256; ++d) acc += ov[d] * fc_w[d * 256 + tid];
    xx[tid] = acc + fc_b[tid] + qin[tid];
  }
  __syncthreads();

  // LayerNorm stats (serial, exact)
  if (tid == 0) {
    float s = 0.f, ss = 0.f;
    for (int j = 0; j < 256; ++j) {
      const float x = xx[j];
      s += x; ss += x * x;
    }
    const float mu = s * (1.0f / 256.0f);
    const float var = ss * (1.0f / 256.0f) - mu * mu;
    stats[0] = mu;
    stats[1] = rsqrtf(var + 1e-5f);
  }
  __syncthreads();
  hcat[tid] = (xx[tid] - stats[0]) * stats[1] * ln_g[tid] + ln_b[tid];
  if (tid < 128) hcat[256 + tid] = src[b * 128 + tid];
  __syncthreads();

  // fc1 + relu
  if (tid < 128) {
    float acc = fc1_b[tid];
    for (int d = 0; d < 384; ++d) acc += hcat[d] * fc1_w[d * 128 + tid];
    h1[tid] = fmaxf(acc, 0.f);
  }
  __syncthreads();

  // fc2 -> merged
  if (tid < 128) {
    float acc = fc2_b[tid];
    for (int d = 0; d < 128; ++d) acc += h1[d] * fc2_w[d * 128 + tid];
    out[b * 128 + tid] = acc;
  }
}

// ---------------------------------------------------------------------------
// FAST PATH (under test via attn_sq): q-proj, qk-proj, attention stream.
__global__ __launch_bounds__(256) void k_qproj(const float* __restrict__ src,
                                               const float* __restrict__ srct,
                                               const float* __restrict__ w_qs,
                                               float* __restrict__ Q) {
  __shared__ float sQ[16 * 256];
  const int tid = threadIdx.x;
  const int rb = blockIdx.x * 16;
  {
    const int r = tid >> 4;
    const int cb = (tid & 15) * 16;
#pragma unroll
    for (int i = 0; i < 4; ++i) {
      const int c = cb + i * 4;
      float4 v = (c < 128) ? *(const float4*)&src[(rb + r) * 128 + c]
                           : *(const float4*)&srct[(rb + r) * 128 + (c - 128)];
      *(float4*)&sQ[r * 256 + c] = v;
    }
  }
  __syncthreads();
  const int rg = tid >> 6;
  const int cg = tid & 63;
  float4 acc[4] = {};
  for (int k = 0; k < 256; k += 4) {
    const float4 w0 = *(const float4*)&w_qs[(k + 0) * 256 + cg * 4];
    const float4 w1 = *(const float4*)&w_qs[(k + 1) * 256 + cg * 4];
    const float4 w2 = *(const float4*)&w_qs[(k + 2) * 256 + cg * 4];
    const float4 w3 = *(const float4*)&w_qs[(k + 3) * 256 + cg * 4];
#pragma unroll
    for (int r = 0; r < 4; ++r) {
      const float4 a = *(const float4*)&sQ[(rg * 4 + r) * 256 + k];
      fma4(acc[r], a.x, w0); fma4(acc[r], a.y, w1);
      fma4(acc[r], a.z, w2); fma4(acc[r], a.w, w3);
    }
  }
#pragma unroll
  for (int r = 0; r < 4; ++r)
    *(float4*)&Q[(rb + rg * 4 + r) * 256 + cg * 4] = acc[r];
}

__global__ __launch_bounds__(256) void k_qkproj(const float* __restrict__ Q,
                                                const float* __restrict__ w_ks,
                                                float* __restrict__ QK) {
  __shared__ float sQ[8 * 256];
  const int tid = threadIdx.x;
  const int rb = blockIdx.x * 8;
#pragma unroll
  for (int i = 0; i < 2; ++i) {
    const int f4 = i * 256 + tid;
    const int r = f4 >> 6;
    const int c = (f4 & 63) * 4;
    *(float4*)&sQ[r * 256 + c] = *(const float4*)&Q[(rb + r) * 256 + c];
  }
  __syncthreads();
  const int rg = tid >> 7;
  const int cg = tid & 127;
  const int h = cg >> 6;
  const int j0 = (cg * 4) & 255;
  float4 acc[4] = {};
  for (int t = 0; t < 128; t += 4) {
    const float4 w0 = *(const float4*)&w_ks[(j0 + 0) * 256 + h * 128 + t];
    const float4 w1 = *(const float4*)&w_ks[(j0 + 1) * 256 + h * 128 + t];
    const float4 w2 = *(const float4*)&w_ks[(j0 + 2) * 256 + h * 128 + t];
    const float4 w3 = *(const float4*)&w_ks[(j0 + 3) * 256 + h * 128 + t];
#pragma unroll
    for (int r = 0; r < 4; ++r) {
      const float4 a = *(const float4*)&sQ[(rg * 4 + r) * 256 + h * 128 + t];
      acc[r].x += dot4(a, w0);
      acc[r].y += dot4(a, w1);
      acc[r].z += dot4(a, w2);
      acc[r].w += dot4(a, w3);
    }
  }
#pragma unroll
  for (int r = 0; r < 4; ++r)
    *(float4*)&QK[(rb + rg * 4 + r) * 512 + cg * 4] = acc[r];
}

__global__ __launch_bounds__(256) void k_attn(const float* __restrict__ seq,
                                              const float* __restrict__ seqt,
                                              const unsigned int* __restrict__ mw,
                                              float* QKS,
                                              float* __restrict__ att) {
  const int tid = threadIdx.x;
  const int lane = tid & 63;
  const int b = blockIdx.x * 4 + (tid >> 6);
  const int mv = (mw[b * 64 + lane] != 0u) ? 1 : 0;
  const float* kin = (lane < 32) ? (seq + b * 8192 + lane * 4)
                                 : (seqt + b * 8192 + (lane - 32) * 4);
  const float4 qk0 = *(const float4*)(QKS + b * 512 + lane * 4);
  const float4 qk1 = *(const float4*)(QKS + b * 512 + 256 + lane * 4);
  float4 s0 = {0.f, 0.f, 0.f, 0.f}, s1 = {0.f, 0.f, 0.f, 0.f};
  float l0 = 0.f, l1 = 0.f, rex0 = 0.f, rex1 = 0.f;
  const float scale = 0.08838834764831845f;  // 1/sqrt(128)
#pragma unroll 8
  for (int n = 0; n < 64; ++n) {
    const float4 kv = *(const float4*)(kin + n * 128);
    float p0 = dot4(kv, qk0);
    float p1 = dot4(kv, qk1);
#pragma unroll
    for (int off = 32; off >= 1; off >>= 1) {
      p0 += __shfl_xor(p0, off);
      p1 += __shfl_xor(p1, off);
    }
    const int mn = __shfl(mv, n);
    const float e0 = mn ? 0.f : __expf(p0 * scale);
    const float e1 = mn ? 0.f : __expf(p1 * scale);
    l0 += e0; l1 += e1;
    fma4(s0, e0, kv);
    fma4(s1, e1, kv);
    rex0 = (lane == n) ? e0 : rex0;
    rex1 = (lane == n) ? e1 : rex1;
  }
  const float i0 = 1.0f / l0;
  const float i1 = 1.0f / l1;
  const float4 o0 = {s0.x * i0, s0.y * i0, s0.z * i0, s0.w * i0};
  const float4 o1 = {s1.x * i1, s1.y * i1, s1.z * i1, s1.w * i1};
  *(float4*)(QKS + b * 512 + lane * 4) = o0;
  *(float4*)(QKS + b * 512 + 256 + lane * 4) = o1;
  att[b * 64 + lane] = rex0 * i0;
  att[4096 * 64 + b * 64 + lane] = rex1 * i1;
}

// ---------------------------------------------------------------------------
extern "C" void kernel_launch(void* const* d_in, const int* in_sizes, int n_in,
                              void* d_out, int out_size, void* d_ws,
                              size_t ws_size, hipStream_t stream) {
  (void)in_sizes; (void)n_in; (void)out_size;
  const float* src = (const float*)d_in[0];
  const float* srct = (const float*)d_in[1];
  const float* seq = (const float*)d_in[2];
  const float* seqt = (const float*)d_in[3];
  const unsigned int* mask = (const unsigned int*)d_in[4];
  const float* w_qs = (const float*)d_in[5];
  const float* w_ks = (const float*)d_in[6];
  const float* w_vs = (const float*)d_in[7];
  const float* fc_w = (const float*)d_in[8];
  const float* fc_b = (const float*)d_in[9];
  const float* ln_g = (const float*)d_in[10];
  const float* ln_b = (const float*)d_in[11];
  const float* fc1_w = (const float*)d_in[12];
  const float* fc1_b = (const float*)d_in[13];
  const float* fc2_w = (const float*)d_in[14];
  const float* fc2_b = (const float*)d_in[15];
  float* out = (float*)d_out;              // merged: 4096x128
  float* att = out + 4096 * 128;           // attn_sq: 8192x64
  const size_t wsNeed = (size_t)(4096 * 256 + 4096 * 512) * sizeof(float);
  const int haveWs = (ws_size >= wsNeed) ? 1 : 0;
  // Output 0 via direct path (writes att only if fast path unavailable).
  k_direct<<<4096, 256, 0, stream>>>(src, srct, seq, seqt, mask, w_qs, w_ks,
                                     w_vs, fc_w, fc_b, ln_g, ln_b, fc1_w,
                                     fc1_b, fc2_w, fc2_b, out, att,
                                     haveWs ? 0 : 1);
  if (haveWs) {
    float* Q = (float*)d_ws;               // 4096x256
    float* QKS = Q + 4096 * 256;           // 4096x512
    k_qproj<<<256, 256, 0, stream>>>(src, srct, w_qs, Q);
    k_qkproj<<<512, 256, 0, stream>>>(Q, w_ks, QKS);
    k_attn<<<1024, 256, 0, stream>>>(seq, seqt, mask, QKS, att);
  }
}

// Round 4
// 469.230 us; speedup vs baseline: 16.2005x; 16.2005x over previous
//
#include <hip/hip_runtime.h>

// TGRec fused forward, MI355X (gfx950), all f32.
// Validated-by-bisection structure (R3):
//   k_qproj -> k_qkproj -> k_attn   : produces attn_sq (output 1) + S
//   k_epi                           : k_direct's validated epilogue stages,
//                                     batched 4/block, consuming S.
// S = sum_n softmax_n * k_in[n]  (associativity: V-projection deferred).

__device__ __forceinline__ void fma4(float4& a, float s, const float4& w) {
  a.x = fmaf(s, w.x, a.x); a.y = fmaf(s, w.y, a.y);
  a.z = fmaf(s, w.z, a.z); a.w = fmaf(s, w.w, a.w);
}
__device__ __forceinline__ float dot4(const float4& a, const float4& b) {
  return a.x * b.x + a.y * b.y + a.z * b.z + a.w * b.w;
}

// ---------------------------------------------------------------------------
// K0a: Q = [src | src_t] @ w_qs   (4096x256 @ 256x256)   [validated R3]
__global__ __launch_bounds__(256) void k_qproj(const float* __restrict__ src,
                                               const float* __restrict__ srct,
                                               const float* __restrict__ w_qs,
                                               float* __restrict__ Q) {
  __shared__ float sQ[16 * 256];
  const int tid = threadIdx.x;
  const int rb = blockIdx.x * 16;
  {
    const int r = tid >> 4;
    const int cb = (tid & 15) * 16;
#pragma unroll
    for (int i = 0; i < 4; ++i) {
      const int c = cb + i * 4;
      float4 v = (c < 128) ? *(const float4*)&src[(rb + r) * 128 + c]
                           : *(const float4*)&srct[(rb + r) * 128 + (c - 128)];
      *(float4*)&sQ[r * 256 + c] = v;
    }
  }
  __syncthreads();
  const int rg = tid >> 6;
  const int cg = tid & 63;
  float4 acc[4] = {};
  for (int k = 0; k < 256; k += 4) {
    const float4 w0 = *(const float4*)&w_qs[(k + 0) * 256 + cg * 4];
    const float4 w1 = *(const float4*)&w_qs[(k + 1) * 256 + cg * 4];
    const float4 w2 = *(const float4*)&w_qs[(k + 2) * 256 + cg * 4];
    const float4 w3 = *(const float4*)&w_qs[(k + 3) * 256 + cg * 4];
#pragma unroll
    for (int r = 0; r < 4; ++r) {
      const float4 a = *(const float4*)&sQ[(rg * 4 + r) * 256 + k];
      fma4(acc[r], a.x, w0); fma4(acc[r], a.y, w1);
      fma4(acc[r], a.z, w2); fma4(acc[r], a.w, w3);
    }
  }
#pragma unroll
  for (int r = 0; r < 4; ++r)
    *(float4*)&Q[(rb + rg * 4 + r) * 256 + cg * 4] = acc[r];
}

// ---------------------------------------------------------------------------
// K0b: QK[b, h*256+j] = sum_d Q[b, h*128+d] * w_ks[j, h*128+d] [validated R3]
__global__ __launch_bounds__(256) void k_qkproj(const float* __restrict__ Q,
                                                const float* __restrict__ w_ks,
                                                float* __restrict__ QK) {
  __shared__ float sQ[8 * 256];
  const int tid = threadIdx.x;
  const int rb = blockIdx.x * 8;
#pragma unroll
  for (int i = 0; i < 2; ++i) {
    const int f4 = i * 256 + tid;
    const int r = f4 >> 6;
    const int c = (f4 & 63) * 4;
    *(float4*)&sQ[r * 256 + c] = *(const float4*)&Q[(rb + r) * 256 + c];
  }
  __syncthreads();
  const int rg = tid >> 7;
  const int cg = tid & 127;
  const int h = cg >> 6;
  const int j0 = (cg * 4) & 255;
  float4 acc[4] = {};
  for (int t = 0; t < 128; t += 4) {
    const float4 w0 = *(const float4*)&w_ks[(j0 + 0) * 256 + h * 128 + t];
    const float4 w1 = *(const float4*)&w_ks[(j0 + 1) * 256 + h * 128 + t];
    const float4 w2 = *(const float4*)&w_ks[(j0 + 2) * 256 + h * 128 + t];
    const float4 w3 = *(const float4*)&w_ks[(j0 + 3) * 256 + h * 128 + t];
#pragma unroll
    for (int r = 0; r < 4; ++r) {
      const float4 a = *(const float4*)&sQ[(rg * 4 + r) * 256 + h * 128 + t];
      acc[r].x += dot4(a, w0);
      acc[r].y += dot4(a, w1);
      acc[r].z += dot4(a, w2);
      acc[r].w += dot4(a, w3);
    }
  }
#pragma unroll
  for (int r = 0; r < 4; ++r)
    *(float4*)&QK[(rb + rg * 4 + r) * 512 + cg * 4] = acc[r];
}

// ---------------------------------------------------------------------------
// K1: attention stream [validated R3 incl. att write]. Lane l owns k_in
// concatenated dims [4l,4l+4); writes normalized S in-place over QK + att.
__global__ __launch_bounds__(256) void k_attn(const float* __restrict__ seq,
                                              const float* __restrict__ seqt,
                                              const unsigned int* __restrict__ mw,
                                              float* QKS,
                                              float* __restrict__ att) {
  const int tid = threadIdx.x;
  const int lane = tid & 63;
  const int b = blockIdx.x * 4 + (tid >> 6);
  const int mv = (mw[b * 64 + lane] != 0u) ? 1 : 0;
  const float* kin = (lane < 32) ? (seq + b * 8192 + lane * 4)
                                 : (seqt + b * 8192 + (lane - 32) * 4);
  const float4 qk0 = *(const float4*)(QKS + b * 512 + lane * 4);
  const float4 qk1 = *(const float4*)(QKS + b * 512 + 256 + lane * 4);
  float4 s0 = {0.f, 0.f, 0.f, 0.f}, s1 = {0.f, 0.f, 0.f, 0.f};
  float l0 = 0.f, l1 = 0.f, rex0 = 0.f, rex1 = 0.f;
  const float scale = 0.08838834764831845f;  // 1/sqrt(128)
#pragma unroll 8
  for (int n = 0; n < 64; ++n) {
    const float4 kv = *(const float4*)(kin + n * 128);
    float p0 = dot4(kv, qk0);
    float p1 = dot4(kv, qk1);
#pragma unroll
    for (int off = 32; off >= 1; off >>= 1) {
      p0 += __shfl_xor(p0, off);
      p1 += __shfl_xor(p1, off);
    }
    const int mn = __shfl(mv, n);
    const float e0 = mn ? 0.f : __expf(p0 * scale);
    const float e1 = mn ? 0.f : __expf(p1 * scale);
    l0 += e0; l1 += e1;
    fma4(s0, e0, kv);
    fma4(s1, e1, kv);
    rex0 = (lane == n) ? e0 : rex0;
    rex1 = (lane == n) ? e1 : rex1;
  }
  const float i0 = 1.0f / l0;
  const float i1 = 1.0f / l1;
  const float4 o0 = {s0.x * i0, s0.y * i0, s0.z * i0, s0.w * i0};
  const float4 o1 = {s1.x * i1, s1.y * i1, s1.z * i1, s1.w * i1};
  *(float4*)(QKS + b * 512 + lane * 4) = o0;
  *(float4*)(QKS + b * 512 + 256 + lane * 4) = o1;
  att[b * 64 + lane] = rex0 * i0;
  att[4096 * 64 + b * 64 + lane] = rex1 * i1;
}

// ---------------------------------------------------------------------------
// K2: epilogue — k_direct's validated stages from sv onward, 4 batches/block.
// sv[g] := S row (head0 dims 0..255, head1 dims 256..511).
__global__ __launch_bounds__(256) void k_epi(
    const float* __restrict__ S, const float* __restrict__ src,
    const float* __restrict__ srct, const float* __restrict__ w_vs,
    const float* __restrict__ fc_w, const float* __restrict__ fc_b,
    const float* __restrict__ ln_g, const float* __restrict__ ln_b,
    const float* __restrict__ fc1_w, const float* __restrict__ fc1_b,
    const float* __restrict__ fc2_w, const float* __restrict__ fc2_b,
    float* __restrict__ out) {
  __shared__ float sv[4][512];
  __shared__ float qin[4][256];
  __shared__ float ov[4][256];
  __shared__ float xx[4][256];
  __shared__ float hcat[4][384];
  __shared__ float h1[4][128];
  __shared__ float stats[4][2];
  const int tid = threadIdx.x;
  const int b0 = blockIdx.x * 4;

  // load S rows: 4 x 512 floats
#pragma unroll
  for (int i = 0; i < 2; ++i) {
    const int f4 = i * 256 + tid;      // 0..511
    const int g = f4 >> 7;
    const int c = (f4 & 127) * 4;
    *(float4*)&sv[g][c] = *(const float4*)&S[(b0 + g) * 512 + c];
  }
  // load q_in = [src | src_t]: 4 x 256 floats
  {
    const int g = tid >> 6;
    const int c = (tid & 63) * 4;
    float4 v = (c < 128) ? *(const float4*)&src[(b0 + g) * 128 + c]
                         : *(const float4*)&srct[(b0 + g) * 128 + (c - 128)];
    *(float4*)&qin[g][c] = v;
  }
  __syncthreads();

  // ov[g][j] = sum_t sv[g][h*256+t] * w_vs[t, j],  h = j>>7   [k_direct stage]
  {
    const int h = tid >> 7;
    float acc[4] = {0.f, 0.f, 0.f, 0.f};
    for (int t = 0; t < 256; ++t) {
      const float w = w_vs[t * 256 + tid];
#pragma unroll
      for (int g = 0; g < 4; ++g) acc[g] = fmaf(sv[g][h * 256 + t], w, acc[g]);
    }
#pragma unroll
    for (int g = 0; g < 4; ++g) ov[g][tid] = acc[g];
  }
  __syncthreads();

  // xx[g][j] = ov[g] @ fc_w[:,j] + fc_b[j] + qin[g][j]        [k_direct stage]
  {
    float acc[4] = {0.f, 0.f, 0.f, 0.f};
    for (int d = 0; d < 256; ++d) {
      const float w = fc_w[d * 256 + tid];
#pragma unroll
      for (int g = 0; g < 4; ++g) acc[g] = fmaf(ov[g][d], w, acc[g]);
    }
    const float fb = fc_b[tid];
#pragma unroll
    for (int g = 0; g < 4; ++g) xx[g][tid] = acc[g] + fb + qin[g][tid];
  }
  __syncthreads();

  // LayerNorm stats (serial per row, exact)                   [k_direct stage]
  if (tid < 4) {
    const int g = tid;
    float s = 0.f, ss = 0.f;
    for (int j = 0; j < 256; ++j) {
      const float x = xx[g][j];
      s += x; ss += x * x;
    }
    const float mu = s * (1.0f / 256.0f);
    const float var = ss * (1.0f / 256.0f) - mu * mu;
    stats[g][0] = mu;
    stats[g][1] = rsqrtf(var + 1e-5f);
  }
  __syncthreads();
  {
    const float gg = ln_g[tid], bb = ln_b[tid];
#pragma unroll
    for (int g = 0; g < 4; ++g)
      hcat[g][tid] = (xx[g][tid] - stats[g][0]) * stats[g][1] * gg + bb;
  }
#pragma unroll
  for (int i = 0; i < 2; ++i) {
    const int idx = i * 256 + tid;     // 0..511
    const int g = idx >> 7, c = idx & 127;
    hcat[g][256 + c] = src[(b0 + g) * 128 + c];
  }
  __syncthreads();

  // fc1 + relu: col = tid&127, two g per thread               [k_direct stage]
  {
    const int col = tid & 127;
    const int gp = (tid >> 7) * 2;
    float acc0 = fc1_b[col], acc1 = acc0;
    for (int d = 0; d < 384; ++d) {
      const float w = fc1_w[d * 128 + col];
      acc0 = fmaf(hcat[gp][d], w, acc0);
      acc1 = fmaf(hcat[gp + 1][d], w, acc1);
    }
    h1[gp][col] = fmaxf(acc0, 0.f);
    h1[gp + 1][col] = fmaxf(acc1, 0.f);
  }
  __syncthreads();

  // fc2 -> merged                                             [k_direct stage]
  {
    const int col = tid & 127;
    const int gp = (tid >> 7) * 2;
    float acc0 = fc2_b[col], acc1 = acc0;
    for (int d = 0; d < 128; ++d) {
      const float w = fc2_w[d * 128 + col];
      acc0 = fmaf(h1[gp][d], w, acc0);
      acc1 = fmaf(h1[gp + 1][d], w, acc1);
    }
    out[(b0 + gp) * 128 + col] = acc0;
    out[(b0 + gp + 1) * 128 + col] = acc1;
  }
}

// ---------------------------------------------------------------------------
extern "C" void kernel_launch(void* const* d_in, const int* in_sizes, int n_in,
                              void* d_out, int out_size, void* d_ws,
                              size_t ws_size, hipStream_t stream) {
  (void)in_sizes; (void)n_in; (void)out_size; (void)ws_size;
  const float* src = (const float*)d_in[0];
  const float* srct = (const float*)d_in[1];
  const float* seq = (const float*)d_in[2];
  const float* seqt = (const float*)d_in[3];
  const unsigned int* mask = (const unsigned int*)d_in[4];
  const float* w_qs = (const float*)d_in[5];
  const float* w_ks = (const float*)d_in[6];
  const float* w_vs = (const float*)d_in[7];
  const float* fc_w = (const float*)d_in[8];
  const float* fc_b = (const float*)d_in[9];
  const float* ln_g = (const float*)d_in[10];
  const float* ln_b = (const float*)d_in[11];
  const float* fc1_w = (const float*)d_in[12];
  const float* fc1_b = (const float*)d_in[13];
  const float* fc2_w = (const float*)d_in[14];
  const float* fc2_b = (const float*)d_in[15];
  float* out = (float*)d_out;              // merged: 4096x128
  float* att = out + 4096 * 128;           // attn_sq: 8192x64
  float* Q = (float*)d_ws;                 // 4096x256
  float* QKS = Q + 4096 * 256;             // 4096x512 (qk, then S in-place)
  k_qproj<<<256, 256, 0, stream>>>(src, srct, w_qs, Q);
  k_qkproj<<<512, 256, 0, stream>>>(Q, w_ks, QKS);
  k_attn<<<1024, 256, 0, stream>>>(seq, seqt, mask, QKS, att);
  k_epi<<<1024, 256, 0, stream>>>(QKS, src, srct, w_vs, fc_w, fc_b, ln_g,
                                  ln_b, fc1_w, fc1_b, fc2_w, fc2_b, out);
}